// Round 12
// baseline (116.968 us; speedup 1.0000x reference)
//
#include <hip/hip_runtime.h>
#include <hip/hip_bf16.h>

// RGCN layer, MI355X (gfx950).
// Stage 0: k_wt — pre-transpose weights to bf16 Wt[r][o][k] (one-time, 16 blocks).
// Stage 1: k_gemm — X2[r][n][o] = nf[n] @ W_r. R11 post-mortem: 31% occupancy
//          (36.9KB LDS -> 4 blk/CU x 4 waves); stores under-issued at 2.5 TB/s.
//          Now 512 thr/block (128 nodes x 4 rels), same LDS -> 4 blk x 8 waves
//          = 32 waves/CU. nf-once registers + LDS-resident W + packed uint2 stores.
// Stage 2a: per-block-private counting sort of edges into 782 dst-buckets (64 nodes).
// Stage 2b: k_nsort — in-bucket counting sort by exact dst node -> per-node CSR noffs.
// Stage 3: k_ngather — per-node rec prefetch (1 coalesced load = 64 edges) + shfl
//          broadcast -> independent X-row loads; 8B/lane, float4 acc, shfl_xor merge.
//
// ws: X2 102.4MB | Wt 128KB | rec 8MB | cntT 800KB | offsT 800KB | bsum 3KB | noffs 200KB

#define NN 50000
#define EE 1000000
#define RR 16
#define NBLK 256            // binning blocks
#define EPB 3907            // ceil(EE/NBLK)
#define BSH 6               // 64 nodes per bucket
#define NBUK 782            // ceil(NN/64)
#define NS (NBUK * NBLK)    // 200192 (= 782 scan_a blocks of 256 exactly)
#define SCAP 2048           // k_nsort LDS record capacity (mean 1279, +21 sigma)

typedef __attribute__((ext_vector_type(8))) short short8;
typedef __attribute__((ext_vector_type(4))) float f32x4;

static __device__ inline unsigned short f2bf(float f) {
  union { __hip_bfloat16 h; unsigned short u; } cv;
  cv.h = __float2bfloat16(f);
  return cv.u;
}
static __device__ inline float bf2f(unsigned short u) {
  union { unsigned i; float f; } cv;
  cv.i = ((unsigned)u) << 16;
  return cv.f;
}

// ---------------- Stage 0: W[r][k][o] fp32 -> Wt[r][o][k] bf16 ----------------
__global__ __launch_bounds__(256) void k_wt(const float* __restrict__ W,
                                            unsigned short* __restrict__ Wt) {
  __shared__ __align__(16) unsigned short Wl[64][72];
  const int r = blockIdx.x, tid = threadIdx.x;
  for (int i = tid; i < 4096; i += 256) Wl[i & 63][i >> 6] = f2bf(W[(r << 12) + i]);
  __syncthreads();
  const int o = tid >> 2, kc = (tid & 3) << 4;
  const short8 v0 = *reinterpret_cast<const short8*>(&Wl[o][kc]);
  const short8 v1 = *reinterpret_cast<const short8*>(&Wl[o][kc + 8]);
  unsigned short* dst = Wt + (r << 12) + (o << 6) + kc;
  *reinterpret_cast<short8*>(dst) = v0;
  *reinterpret_cast<short8*>(dst + 8) = v1;
}

// ---------------- Stage 1: dense transform, 512 threads / 128 nodes ----------------
// Grid (391, 4). Block: 8 waves; wave wv owns nodes blockIdx.x*128 + wv*16 + lr.
// A = W tile from LDS (row = o = c*16 + lr, k = lg*8+j)
// B = nf tile in registers (col = node = lr, k = lg*8+j), built once.
// D: row = o_local = lg*4+reg (4 consecutive o in-lane), col = node = lr.
__global__ __launch_bounds__(512) void k_gemm(const float* __restrict__ nf,
                                              const unsigned short* __restrict__ Wt,
                                              unsigned short* __restrict__ X) {
  __shared__ __align__(16) unsigned short Wl[4][64][72];  // 36,864 B
  const int tid = threadIdx.x;
  const int lane = tid & 63, wv = tid >> 6;
  const int lr = lane & 15, lg = lane >> 4;
  const int node = (blockIdx.x << 7) + (wv << 4) + lr;
  const int r0 = blockIdx.y << 2;
  // stage 4 relations: 512 threads x one short8 (16B) each per relation
  #pragma unroll
  for (int rr = 0; rr < 4; ++rr) {
    const short8 v = *reinterpret_cast<const short8*>(
        Wt + (((size_t)(r0 + rr)) << 12) + (tid << 3));
    *reinterpret_cast<short8*>(&Wl[rr][tid >> 3][(tid & 7) << 3]) = v;
  }
  short8 bf0, bf1;
  if (node < NN) {
    const float* ap = nf + (size_t)node * 64 + lg * 8;
    float4 v0 = *reinterpret_cast<const float4*>(ap);
    float4 v1 = *reinterpret_cast<const float4*>(ap + 4);
    float4 v2 = *reinterpret_cast<const float4*>(ap + 32);
    float4 v3 = *reinterpret_cast<const float4*>(ap + 36);
    bf0 = short8{(short)f2bf(v0.x), (short)f2bf(v0.y), (short)f2bf(v0.z), (short)f2bf(v0.w),
                 (short)f2bf(v1.x), (short)f2bf(v1.y), (short)f2bf(v1.z), (short)f2bf(v1.w)};
    bf1 = short8{(short)f2bf(v2.x), (short)f2bf(v2.y), (short)f2bf(v2.z), (short)f2bf(v2.w),
                 (short)f2bf(v3.x), (short)f2bf(v3.y), (short)f2bf(v3.z), (short)f2bf(v3.w)};
  } else {
    bf0 = short8{0, 0, 0, 0, 0, 0, 0, 0};
    bf1 = bf0;
  }
  __syncthreads();
  #pragma unroll
  for (int rr = 0; rr < 4; ++rr) {
    const int r = r0 + rr;
    short8 a[8];
    #pragma unroll
    for (int c = 0; c < 4; ++c) {
      a[2 * c] = *reinterpret_cast<const short8*>(&Wl[rr][(c << 4) + lr][lg << 3]);
      a[2 * c + 1] = *reinterpret_cast<const short8*>(&Wl[rr][(c << 4) + lr][32 + (lg << 3)]);
    }
    f32x4 acc[4];
    #pragma unroll
    for (int c = 0; c < 4; ++c) {
      acc[c] = f32x4{0.f, 0.f, 0.f, 0.f};
      acc[c] = __builtin_amdgcn_mfma_f32_16x16x32_bf16(a[2 * c], bf0, acc[c], 0, 0, 0);
      acc[c] = __builtin_amdgcn_mfma_f32_16x16x32_bf16(a[2 * c + 1], bf1, acc[c], 0, 0, 0);
    }
    if (node < NN) {
      #pragma unroll
      for (int c = 0; c < 4; ++c) {
        uint2 p;
        p.x = (unsigned)f2bf(acc[c][0]) | ((unsigned)f2bf(acc[c][1]) << 16);
        p.y = (unsigned)f2bf(acc[c][2]) | ((unsigned)f2bf(acc[c][3]) << 16);
        *reinterpret_cast<uint2*>(&X[((size_t)r * NN + node) * 64 + (c << 4) + (lg << 2)]) = p;
      }
    }
  }
}

// ---------------- Stage 2a: per-block-private bucket sort ----------------
__global__ __launch_bounds__(256) void k_hist(const int* __restrict__ edst,
                                              int* __restrict__ cntT) {
  __shared__ int cnt[NBUK];
  const int bl = blockIdx.x, tid = threadIdx.x;
  for (int i = tid; i < NBUK; i += 256) cnt[i] = 0;
  __syncthreads();
  const int e0 = bl * EPB, e1 = min(EE, e0 + EPB);
  for (int e = e0 + tid; e < e1; e += 256) atomicAdd(&cnt[edst[e] >> BSH], 1);
  __syncthreads();
  for (int i = tid; i < NBUK; i += 256) cntT[i * NBLK + bl] = cnt[i];
}

__global__ __launch_bounds__(256) void k_scan_a(const int* __restrict__ cntT,
                                                int* __restrict__ offsT,
                                                int* __restrict__ bsum) {
  __shared__ int s[256];
  const int t = threadIdx.x;
  const int i = blockIdx.x * 256 + t;
  const int v = cntT[i];
  s[t] = v;
  __syncthreads();
  #pragma unroll
  for (int off = 1; off < 256; off <<= 1) {
    const int x = (t >= off) ? s[t - off] : 0;
    __syncthreads();
    s[t] += x;
    __syncthreads();
  }
  offsT[i] = s[t] - v;
  if (t == 255) bsum[blockIdx.x] = s[255];
}

__global__ __launch_bounds__(1024) void k_scan_b(int* __restrict__ bsum) {
  __shared__ int s[1024];
  const int t = threadIdx.x;
  const int v = (t < NBUK) ? bsum[t] : 0;
  s[t] = v;
  __syncthreads();
  #pragma unroll
  for (int off = 1; off < 1024; off <<= 1) {
    const int x = (t >= off) ? s[t - off] : 0;
    __syncthreads();
    s[t] += x;
    __syncthreads();
  }
  if (t < NBUK) bsum[t] = s[t] - v;
}

__global__ __launch_bounds__(256) void k_scan_c(int* __restrict__ offsT,
                                                const int* __restrict__ bsum) {
  const int i = blockIdx.x * 256 + threadIdx.x;
  offsT[i] += bsum[blockIdx.x];
}

__global__ __launch_bounds__(256) void k_scatter(const int* __restrict__ esrc,
                                                 const int* __restrict__ edst,
                                                 const int* __restrict__ etyp,
                                                 const float* __restrict__ enorm,
                                                 const int* __restrict__ offsT,
                                                 uint2* __restrict__ rec) {
  __shared__ int cur[NBUK];
  const int bl = blockIdx.x, tid = threadIdx.x;
  for (int i = tid; i < NBUK; i += 256) cur[i] = offsT[i * NBLK + bl];
  __syncthreads();
  const int e0 = bl * EPB, e1 = min(EE, e0 + EPB);
  for (int e = e0 + tid; e < e1; e += 256) {
    const int d = edst[e];
    const int pos = atomicAdd(&cur[d >> BSH], 1);
    rec[pos] = make_uint2(((unsigned)(etyp[e] * NN + esrc[e]) << 6) | (unsigned)(d & 63),
                          __float_as_uint(enorm[e]));
  }
}

// ---------------- Stage 2b: in-bucket sort by exact dst node (in place) ----------------
__global__ __launch_bounds__(256) void k_nsort(const int* __restrict__ offsT,
                                               uint2* __restrict__ rec,
                                               int* __restrict__ noffs) {
  __shared__ uint2 sbuf[SCAP];  // 16 KB
  __shared__ int cnt[64], cur[64];
  const int bu = blockIdx.x, tid = threadIdx.x;
  const int s = offsT[bu * NBLK];
  const int e = (bu == NBUK - 1) ? EE : offsT[(bu + 1) * NBLK];
  const int n = e - s;
  if (tid < 64) cnt[tid] = 0;
  __syncthreads();
  if (n > SCAP) {
    if (tid < 64) noffs[(bu << BSH) + tid] = -1;
    return;
  }
  for (int i = tid; i < n; i += 256) {
    const uint2 r = rec[s + i];
    sbuf[i] = r;
    atomicAdd(&cnt[r.x & 63u], 1);
  }
  __syncthreads();
  if (tid < 64) {
    const int v = cnt[tid];
    int x = v;
    #pragma unroll
    for (int off = 1; off < 64; off <<= 1) {
      const int t = __shfl_up(x, off, 64);
      if (tid >= off) x += t;
    }
    cur[tid] = x - v;
    noffs[(bu << BSH) + tid] = s + x - v;
  }
  __syncthreads();
  for (int i = tid; i < n; i += 256) {
    const uint2 r = sbuf[i];
    const int pos = atomicAdd(&cur[r.x & 63u], 1);
    rec[s + pos] = r;
  }
}

// ---------------- Stage 3: wave-per-node gather, rec-prefetch + shfl ----------------
__global__ __launch_bounds__(256) void k_ngather(const uint2* __restrict__ rec,
                                                 const int* __restrict__ noffs,
                                                 const int* __restrict__ offsT,
                                                 const unsigned short* __restrict__ X,
                                                 const float* __restrict__ bias,
                                                 float* __restrict__ out) {
  const int w = (int)((blockIdx.x * 256 + threadIdx.x) >> 6);  // node id
  const int lane = threadIdx.x & 63;
  if (w >= NN) return;
  const int quarter = lane >> 4, d4 = lane & 15;
  const int bu = w >> BSH;
  float4 acc = {0.f, 0.f, 0.f, 0.f};
  const int jb = noffs[w];
  if (jb >= 0) {
    const int bend = (bu == NBUK - 1) ? EE : offsT[(bu + 1) * NBLK];
    const int je = ((w & 63) == 63) ? bend : noffs[w + 1];
    for (int base = jb; base < je; base += 64) {
      const int deg = min(64, je - base);
      unsigned rxs = 0;
      float rns = 0.f;
      if (lane < deg) {
        const uint2 r = rec[base + lane];
        rxs = r.x >> 6;  // X row id
        rns = __uint_as_float(r.y);
      }
      int u = 0;
      for (; u + 8 <= deg; u += 8) {  // 8 edges per body, 2 independent X loads
        const int i0 = u + quarter, i1 = u + 4 + quarter;
        const unsigned row0 = (unsigned)__shfl((int)rxs, i0, 64);
        const float n0 = __shfl(rns, i0, 64);
        const unsigned row1 = (unsigned)__shfl((int)rxs, i1, 64);
        const float n1 = __shfl(rns, i1, 64);
        const uint2 x0 = *reinterpret_cast<const uint2*>(X + (size_t)row0 * 64 + (d4 << 2));
        const uint2 x1 = *reinterpret_cast<const uint2*>(X + (size_t)row1 * 64 + (d4 << 2));
        acc.x = fmaf(n0, bf2f((unsigned short)(x0.x & 0xffffu)), acc.x);
        acc.y = fmaf(n0, bf2f((unsigned short)(x0.x >> 16)), acc.y);
        acc.z = fmaf(n0, bf2f((unsigned short)(x0.y & 0xffffu)), acc.z);
        acc.w = fmaf(n0, bf2f((unsigned short)(x0.y >> 16)), acc.w);
        acc.x = fmaf(n1, bf2f((unsigned short)(x1.x & 0xffffu)), acc.x);
        acc.y = fmaf(n1, bf2f((unsigned short)(x1.x >> 16)), acc.y);
        acc.z = fmaf(n1, bf2f((unsigned short)(x1.y & 0xffffu)), acc.z);
        acc.w = fmaf(n1, bf2f((unsigned short)(x1.y >> 16)), acc.w);
      }
      for (; u < deg; u += 4) {  // remainder: clamp + zero-norm for invalid quarters
        const int i = u + quarter;
        const int ic = min(i, deg - 1);
        const unsigned row = (unsigned)__shfl((int)rxs, ic, 64);
        float n = __shfl(rns, ic, 64);
        n = (i < deg) ? n : 0.f;
        const uint2 x = *reinterpret_cast<const uint2*>(X + (size_t)row * 64 + (d4 << 2));
        acc.x = fmaf(n, bf2f((unsigned short)(x.x & 0xffffu)), acc.x);
        acc.y = fmaf(n, bf2f((unsigned short)(x.x >> 16)), acc.y);
        acc.z = fmaf(n, bf2f((unsigned short)(x.y & 0xffffu)), acc.z);
        acc.w = fmaf(n, bf2f((unsigned short)(x.y >> 16)), acc.w);
      }
    }
  } else {
    // oversized-bucket fallback: quarter-0 lanes filter-scan the whole bucket
    if (quarter == 0) {
      const int s = offsT[bu * NBLK];
      const int e = (bu == NBUK - 1) ? EE : offsT[(bu + 1) * NBLK];
      const unsigned dl = (unsigned)(w & 63);
      for (int j = s; j < e; ++j) {
        const uint2 r = rec[j];
        if ((r.x & 63u) == dl) {
          const float n = __uint_as_float(r.y);
          const uint2 x =
              *reinterpret_cast<const uint2*>(X + (size_t)(r.x >> 6) * 64 + (d4 << 2));
          acc.x = fmaf(n, bf2f((unsigned short)(x.x & 0xffffu)), acc.x);
          acc.y = fmaf(n, bf2f((unsigned short)(x.x >> 16)), acc.y);
          acc.z = fmaf(n, bf2f((unsigned short)(x.y & 0xffffu)), acc.z);
          acc.w = fmaf(n, bf2f((unsigned short)(x.y >> 16)), acc.w);
        }
      }
    }
  }
  // merge quarters: lanes {d4, d4+16, d4+32, d4+48} hold same dims
  acc.x += __shfl_xor(acc.x, 16, 64);
  acc.y += __shfl_xor(acc.y, 16, 64);
  acc.z += __shfl_xor(acc.z, 16, 64);
  acc.w += __shfl_xor(acc.w, 16, 64);
  acc.x += __shfl_xor(acc.x, 32, 64);
  acc.y += __shfl_xor(acc.y, 32, 64);
  acc.z += __shfl_xor(acc.z, 32, 64);
  acc.w += __shfl_xor(acc.w, 32, 64);
  if (quarter == 0) {
    const float4 b = reinterpret_cast<const float4*>(bias)[d4];
    float4 o;
    o.x = fmaxf(acc.x + b.x, 0.f);
    o.y = fmaxf(acc.y + b.y, 0.f);
    o.z = fmaxf(acc.z + b.z, 0.f);
    o.w = fmaxf(acc.w + b.w, 0.f);
    reinterpret_cast<float4*>(out)[(size_t)w * 16 + d4] = o;
  }
}

extern "C" void kernel_launch(void* const* d_in, const int* in_sizes, int n_in,
                              void* d_out, int out_size, void* d_ws, size_t ws_size,
                              hipStream_t stream) {
  const float* nf = (const float*)d_in[0];
  const int* esrc = (const int*)d_in[1];
  const int* edst = (const int*)d_in[2];
  const int* etyp = (const int*)d_in[3];
  const float* enorm = (const float*)d_in[4];
  const float* W = (const float*)d_in[5];
  const float* bias = (const float*)d_in[6];
  float* out = (float*)d_out;

  char* ws = (char*)d_ws;
  unsigned short* X = (unsigned short*)ws;        // 102,400,000 B
  unsigned short* Wt = (unsigned short*)(ws + 102400000);  // 131,072 B
  uint2* rec = (uint2*)(ws + 102531072);          //   8,000,000 B
  int* cntT = (int*)(ws + 110531072);             //     800,768 B
  int* offsT = (int*)(ws + 111331840);            //     800,768 B
  int* bsum = (int*)(ws + 112132608);             //       3,128 B
  int* noffs = (int*)(ws + 112135736);            //     200,192 B

  k_wt<<<RR, 256, 0, stream>>>(W, Wt);
  dim3 g1((NN + 127) / 128, 4);
  k_gemm<<<g1, 512, 0, stream>>>(nf, Wt, X);

  k_hist<<<NBLK, 256, 0, stream>>>(edst, cntT);
  k_scan_a<<<NS / 256, 256, 0, stream>>>(cntT, offsT, bsum);
  k_scan_b<<<1, 1024, 0, stream>>>(bsum);
  k_scan_c<<<NS / 256, 256, 0, stream>>>(offsT, bsum);
  k_scatter<<<NBLK, 256, 0, stream>>>(esrc, edst, etyp, enorm, offsT, rec);
  k_nsort<<<NBUK, 256, 0, stream>>>(offsT, rec, noffs);

  k_ngather<<<(NN * 64 + 255) / 256, 256, 0, stream>>>(rec, noffs, offsT, X, bias, out);
}

// Round 13
// 109.453 us; speedup vs baseline: 1.0687x; 1.0687x over previous
//
#include <hip/hip_runtime.h>
#include <hip/hip_bf16.h>

// RGCN layer, MI355X (gfx950).
// R13: launch-graph restructure (R12 post-mortem: gemm is at a ~3 TB/s traffic wall,
// invariant to occupancy 31->48% -- stop tuning it; cut pipeline overhead instead).
//  K1 k_gemm_hist: blocks 0..255 = edge histogram (hides under gemm); blocks 256.. =
//     R11-proven gemm (256 thr, 64 nodes x 4 rels, LDS W staged with INLINE fp32->bf16
//     conversion -- k_wt eliminated).
//  K2 k_scan_a: per-bucket scan of 256 per-block counts (block == bucket).
//  K3 k_scan_b: scan 782 bucket totals -> bsum2[] global bucket starts (+ bsum2[NBUK]=EE).
//  K4 k_scatter: private counting-sort scatter; cursor = offsT_raw + bsum2[bucket]
//     (k_scan_c algebraically eliminated: offsT_raw[bu*256]==0).
//  K5 k_nsort: in-bucket sort by exact dst node -> per-node CSR noffs.
//  K6 k_ngather: wave-per-node rec-prefetch + shfl broadcast gather + bias + relu.
//
// ws: X 102.4MB | rec 8MB | cntT 800KB | offsT 800KB | bsum 3.1KB | bsum2 3.1KB | noffs 200KB

#define NN 50000
#define EE 1000000
#define RR 16
#define NBLK 256            // binning blocks (hist/scatter)
#define EPB 3907            // ceil(EE/NBLK)
#define BSH 6               // 64 nodes per bucket
#define NBUK 782            // ceil(NN/64)
#define NS (NBUK * NBLK)    // 200192 (= 782 scan_a blocks of 256 exactly)
#define SCAP 2048           // k_nsort LDS record capacity (mean 1279, +21 sigma)

typedef __attribute__((ext_vector_type(8))) short short8;
typedef __attribute__((ext_vector_type(4))) float f32x4;

static __device__ inline unsigned short f2bf(float f) {
  union { __hip_bfloat16 h; unsigned short u; } cv;
  cv.h = __float2bfloat16(f);
  return cv.u;
}
static __device__ inline float bf2f(unsigned short u) {
  union { unsigned i; float f; } cv;
  cv.i = ((unsigned)u) << 16;
  return cv.f;
}

// ---------------- K1: fused edge-histogram + dense transform ----------------
// Blocks [0, NBLK): histogram of edst into 782 buckets (per-block-private counts).
// Blocks [NBLK, NBLK + NBUK*4): gemm, bx = (bid-NBLK)>>2, r0 = ((bid-NBLK)&3)<<2.
// Gemm: A = W tile from LDS (row=o=c*16+lr, k=lg*8+j); B = nf in regs (col=node=lr);
// D: row = o_local = lg*4+reg (4 consecutive o in-lane), col = node = lr.
__global__ __launch_bounds__(256) void k_gemm_hist(const float* __restrict__ nf,
                                                   const float* __restrict__ W,
                                                   const int* __restrict__ edst,
                                                   unsigned short* __restrict__ X,
                                                   int* __restrict__ cntT) {
  __shared__ __align__(16) char smem[4 * 64 * 72 * 2];  // 36,864 B union
  const int bid = blockIdx.x, tid = threadIdx.x;
  if (bid < NBLK) {
    // ---- histogram path ----
    int* cnt = reinterpret_cast<int*>(smem);
    for (int i = tid; i < NBUK; i += 256) cnt[i] = 0;
    __syncthreads();
    const int e0 = bid * EPB, e1 = min(EE, e0 + EPB);
    for (int e = e0 + tid; e < e1; e += 256) atomicAdd(&cnt[edst[e] >> BSH], 1);
    __syncthreads();
    for (int i = tid; i < NBUK; i += 256) cntT[i * NBLK + bid] = cnt[i];
    return;
  }
  // ---- gemm path ----
  auto Wl = reinterpret_cast<unsigned short(*)[64][72]>(smem);
  const int g = bid - NBLK;
  const int bx = g >> 2, r0 = (g & 3) << 2;
  const int lane = tid & 63, wv = tid >> 6;
  const int lr = lane & 15, lg = lane >> 4;
  const int node = (bx << 6) + (wv << 4) + lr;
  // stage W[r0..r0+3] fp32 -> LDS bf16 transposed [rr][o][k] (inline, no k_wt)
  for (int i = tid; i < 16384; i += 256) {
    const int rr = i >> 12, rem = i & 4095;  // rem = k*64 + o
    Wl[rr][rem & 63][rem >> 6] = f2bf(W[(((size_t)(r0 + rr)) << 12) + rem]);
  }
  short8 bf0, bf1;
  if (node < NN) {
    const float* ap = nf + (size_t)node * 64 + lg * 8;
    float4 v0 = *reinterpret_cast<const float4*>(ap);
    float4 v1 = *reinterpret_cast<const float4*>(ap + 4);
    float4 v2 = *reinterpret_cast<const float4*>(ap + 32);
    float4 v3 = *reinterpret_cast<const float4*>(ap + 36);
    bf0 = short8{(short)f2bf(v0.x), (short)f2bf(v0.y), (short)f2bf(v0.z), (short)f2bf(v0.w),
                 (short)f2bf(v1.x), (short)f2bf(v1.y), (short)f2bf(v1.z), (short)f2bf(v1.w)};
    bf1 = short8{(short)f2bf(v2.x), (short)f2bf(v2.y), (short)f2bf(v2.z), (short)f2bf(v2.w),
                 (short)f2bf(v3.x), (short)f2bf(v3.y), (short)f2bf(v3.z), (short)f2bf(v3.w)};
  } else {
    bf0 = short8{0, 0, 0, 0, 0, 0, 0, 0};
    bf1 = bf0;
  }
  __syncthreads();
  #pragma unroll
  for (int rr = 0; rr < 4; ++rr) {
    const int r = r0 + rr;
    short8 a[8];
    #pragma unroll
    for (int c = 0; c < 4; ++c) {
      a[2 * c] = *reinterpret_cast<const short8*>(&Wl[rr][(c << 4) + lr][lg << 3]);
      a[2 * c + 1] = *reinterpret_cast<const short8*>(&Wl[rr][(c << 4) + lr][32 + (lg << 3)]);
    }
    f32x4 acc[4];
    #pragma unroll
    for (int c = 0; c < 4; ++c) {
      acc[c] = f32x4{0.f, 0.f, 0.f, 0.f};
      acc[c] = __builtin_amdgcn_mfma_f32_16x16x32_bf16(a[2 * c], bf0, acc[c], 0, 0, 0);
      acc[c] = __builtin_amdgcn_mfma_f32_16x16x32_bf16(a[2 * c + 1], bf1, acc[c], 0, 0, 0);
    }
    if (node < NN) {
      #pragma unroll
      for (int c = 0; c < 4; ++c) {
        uint2 p;
        p.x = (unsigned)f2bf(acc[c][0]) | ((unsigned)f2bf(acc[c][1]) << 16);
        p.y = (unsigned)f2bf(acc[c][2]) | ((unsigned)f2bf(acc[c][3]) << 16);
        *reinterpret_cast<uint2*>(&X[((size_t)r * NN + node) * 64 + (c << 4) + (lg << 2)]) = p;
      }
    }
  }
}

// ---------------- K2: per-bucket scan of per-block counts ----------------
// Block i == bucket i: scans cntT[i*256 .. i*256+255] (counts of binning blocks).
__global__ __launch_bounds__(256) void k_scan_a(const int* __restrict__ cntT,
                                                int* __restrict__ offsT,
                                                int* __restrict__ bsum) {
  __shared__ int s[256];
  const int t = threadIdx.x;
  const int i = blockIdx.x * 256 + t;
  const int v = cntT[i];
  s[t] = v;
  __syncthreads();
  #pragma unroll
  for (int off = 1; off < 256; off <<= 1) {
    const int x = (t >= off) ? s[t - off] : 0;
    __syncthreads();
    s[t] += x;
    __syncthreads();
  }
  offsT[i] = s[t] - v;  // exclusive within bucket (raw)
  if (t == 255) bsum[blockIdx.x] = s[255];  // bucket total
}

// ---------------- K3: scan bucket totals -> global bucket starts ----------------
__global__ __launch_bounds__(1024) void k_scan_b(const int* __restrict__ bsum,
                                                 int* __restrict__ bsum2) {
  __shared__ int s[1024];
  const int t = threadIdx.x;
  const int v = (t < NBUK) ? bsum[t] : 0;
  s[t] = v;
  __syncthreads();
  #pragma unroll
  for (int off = 1; off < 1024; off <<= 1) {
    const int x = (t >= off) ? s[t - off] : 0;
    __syncthreads();
    s[t] += x;
    __syncthreads();
  }
  if (t < NBUK) bsum2[t] = s[t] - v;  // global start of bucket t
  if (t == NBUK) bsum2[NBUK] = EE;
}

// ---------------- K4: private counting-sort scatter ----------------
__global__ __launch_bounds__(256) void k_scatter(const int* __restrict__ esrc,
                                                 const int* __restrict__ edst,
                                                 const int* __restrict__ etyp,
                                                 const float* __restrict__ enorm,
                                                 const int* __restrict__ offsT,
                                                 const int* __restrict__ bsum2,
                                                 uint2* __restrict__ rec) {
  __shared__ int cur[NBUK];
  const int bl = blockIdx.x, tid = threadIdx.x;
  for (int i = tid; i < NBUK; i += 256) cur[i] = offsT[i * NBLK + bl] + bsum2[i];
  __syncthreads();
  const int e0 = bl * EPB, e1 = min(EE, e0 + EPB);
  for (int e = e0 + tid; e < e1; e += 256) {
    const int d = edst[e];
    const int pos = atomicAdd(&cur[d >> BSH], 1);
    // pack: (typ*NN+src)<<6 | dstlow  (r.x>>6 == X row id, typ-major layout)
    rec[pos] = make_uint2(((unsigned)(etyp[e] * NN + esrc[e]) << 6) | (unsigned)(d & 63),
                          __float_as_uint(enorm[e]));
  }
}

// ---------------- K5: in-bucket sort by exact dst node (in place) ----------------
__global__ __launch_bounds__(256) void k_nsort(const int* __restrict__ bsum2,
                                               uint2* __restrict__ rec,
                                               int* __restrict__ noffs) {
  __shared__ uint2 sbuf[SCAP];  // 16 KB
  __shared__ int cnt[64], cur[64];
  const int bu = blockIdx.x, tid = threadIdx.x;
  const int s = bsum2[bu];
  const int e = bsum2[bu + 1];
  const int n = e - s;
  if (tid < 64) cnt[tid] = 0;
  __syncthreads();
  if (n > SCAP) {  // ~impossible overflow: leave unsorted, mark for slow gather
    if (tid < 64) noffs[(bu << BSH) + tid] = -1;
    return;
  }
  for (int i = tid; i < n; i += 256) {
    const uint2 r = rec[s + i];
    sbuf[i] = r;
    atomicAdd(&cnt[r.x & 63u], 1);  // native ds_add_u32
  }
  __syncthreads();
  if (tid < 64) {
    const int v = cnt[tid];
    int x = v;
    #pragma unroll
    for (int off = 1; off < 64; off <<= 1) {
      const int t = __shfl_up(x, off, 64);
      if (tid >= off) x += t;
    }
    cur[tid] = x - v;
    noffs[(bu << BSH) + tid] = s + x - v;
  }
  __syncthreads();
  for (int i = tid; i < n; i += 256) {
    const uint2 r = sbuf[i];
    const int pos = atomicAdd(&cur[r.x & 63u], 1);
    rec[s + pos] = r;
  }
}

// ---------------- K6: wave-per-node gather, rec-prefetch + shfl ----------------
__global__ __launch_bounds__(256) void k_ngather(const uint2* __restrict__ rec,
                                                 const int* __restrict__ noffs,
                                                 const int* __restrict__ bsum2,
                                                 const unsigned short* __restrict__ X,
                                                 const float* __restrict__ bias,
                                                 float* __restrict__ out) {
  const int w = (int)((blockIdx.x * 256 + threadIdx.x) >> 6);  // node id
  const int lane = threadIdx.x & 63;
  if (w >= NN) return;
  const int quarter = lane >> 4, d4 = lane & 15;
  const int bu = w >> BSH;
  float4 acc = {0.f, 0.f, 0.f, 0.f};
  const int jb = noffs[w];
  if (jb >= 0) {
    const int je = ((w & 63) == 63) ? bsum2[bu + 1] : noffs[w + 1];
    for (int base = jb; base < je; base += 64) {
      const int deg = min(64, je - base);
      unsigned rxs = 0;
      float rns = 0.f;
      if (lane < deg) {
        const uint2 r = rec[base + lane];
        rxs = r.x >> 6;  // X row id
        rns = __uint_as_float(r.y);
      }
      int u = 0;
      for (; u + 8 <= deg; u += 8) {  // 8 edges per body, 2 independent X loads
        const int i0 = u + quarter, i1 = u + 4 + quarter;
        const unsigned row0 = (unsigned)__shfl((int)rxs, i0, 64);
        const float n0 = __shfl(rns, i0, 64);
        const unsigned row1 = (unsigned)__shfl((int)rxs, i1, 64);
        const float n1 = __shfl(rns, i1, 64);
        const uint2 x0 = *reinterpret_cast<const uint2*>(X + (size_t)row0 * 64 + (d4 << 2));
        const uint2 x1 = *reinterpret_cast<const uint2*>(X + (size_t)row1 * 64 + (d4 << 2));
        acc.x = fmaf(n0, bf2f((unsigned short)(x0.x & 0xffffu)), acc.x);
        acc.y = fmaf(n0, bf2f((unsigned short)(x0.x >> 16)), acc.y);
        acc.z = fmaf(n0, bf2f((unsigned short)(x0.y & 0xffffu)), acc.z);
        acc.w = fmaf(n0, bf2f((unsigned short)(x0.y >> 16)), acc.w);
        acc.x = fmaf(n1, bf2f((unsigned short)(x1.x & 0xffffu)), acc.x);
        acc.y = fmaf(n1, bf2f((unsigned short)(x1.x >> 16)), acc.y);
        acc.z = fmaf(n1, bf2f((unsigned short)(x1.y & 0xffffu)), acc.z);
        acc.w = fmaf(n1, bf2f((unsigned short)(x1.y >> 16)), acc.w);
      }
      for (; u < deg; u += 4) {  // remainder: clamp + zero-norm for invalid quarters
        const int i = u + quarter;
        const int ic = min(i, deg - 1);
        const unsigned row = (unsigned)__shfl((int)rxs, ic, 64);
        float n = __shfl(rns, ic, 64);
        n = (i < deg) ? n : 0.f;
        const uint2 x = *reinterpret_cast<const uint2*>(X + (size_t)row * 64 + (d4 << 2));
        acc.x = fmaf(n, bf2f((unsigned short)(x.x & 0xffffu)), acc.x);
        acc.y = fmaf(n, bf2f((unsigned short)(x.x >> 16)), acc.y);
        acc.z = fmaf(n, bf2f((unsigned short)(x.y & 0xffffu)), acc.z);
        acc.w = fmaf(n, bf2f((unsigned short)(x.y >> 16)), acc.w);
      }
    }
  } else {
    // oversized-bucket fallback: quarter-0 lanes filter-scan the whole bucket
    if (quarter == 0) {
      const int s = bsum2[bu];
      const int e = bsum2[bu + 1];
      const unsigned dl = (unsigned)(w & 63);
      for (int j = s; j < e; ++j) {
        const uint2 r = rec[j];
        if ((r.x & 63u) == dl) {
          const float n = __uint_as_float(r.y);
          const uint2 x =
              *reinterpret_cast<const uint2*>(X + (size_t)(r.x >> 6) * 64 + (d4 << 2));
          acc.x = fmaf(n, bf2f((unsigned short)(x.x & 0xffffu)), acc.x);
          acc.y = fmaf(n, bf2f((unsigned short)(x.x >> 16)), acc.y);
          acc.z = fmaf(n, bf2f((unsigned short)(x.y & 0xffffu)), acc.z);
          acc.w = fmaf(n, bf2f((unsigned short)(x.y >> 16)), acc.w);
        }
      }
    }
  }
  // merge quarters: lanes {d4, d4+16, d4+32, d4+48} hold same dims
  acc.x += __shfl_xor(acc.x, 16, 64);
  acc.y += __shfl_xor(acc.y, 16, 64);
  acc.z += __shfl_xor(acc.z, 16, 64);
  acc.w += __shfl_xor(acc.w, 16, 64);
  acc.x += __shfl_xor(acc.x, 32, 64);
  acc.y += __shfl_xor(acc.y, 32, 64);
  acc.z += __shfl_xor(acc.z, 32, 64);
  acc.w += __shfl_xor(acc.w, 32, 64);
  if (quarter == 0) {
    const float4 b = reinterpret_cast<const float4*>(bias)[d4];
    float4 o;
    o.x = fmaxf(acc.x + b.x, 0.f);
    o.y = fmaxf(acc.y + b.y, 0.f);
    o.z = fmaxf(acc.z + b.z, 0.f);
    o.w = fmaxf(acc.w + b.w, 0.f);
    reinterpret_cast<float4*>(out)[(size_t)w * 16 + d4] = o;
  }
}

extern "C" void kernel_launch(void* const* d_in, const int* in_sizes, int n_in,
                              void* d_out, int out_size, void* d_ws, size_t ws_size,
                              hipStream_t stream) {
  const float* nf = (const float*)d_in[0];
  const int* esrc = (const int*)d_in[1];
  const int* edst = (const int*)d_in[2];
  const int* etyp = (const int*)d_in[3];
  const float* enorm = (const float*)d_in[4];
  const float* W = (const float*)d_in[5];
  const float* bias = (const float*)d_in[6];
  float* out = (float*)d_out;

  char* ws = (char*)d_ws;
  unsigned short* X = (unsigned short*)ws;        // 102,400,000 B
  uint2* rec = (uint2*)(ws + 102400000);          //   8,000,000 B
  int* cntT = (int*)(ws + 110400000);             //     800,768 B
  int* offsT = (int*)(ws + 111200768);            //     800,768 B
  int* bsum = (int*)(ws + 112001536);             //       3,128 B
  int* bsum2 = (int*)(ws + 112004664);            //       3,132 B
  int* noffs = (int*)(ws + 112007796);            //     200,192 B

  k_gemm_hist<<<NBLK + NBUK * 4, 256, 0, stream>>>(nf, W, edst, X, cntT);
  k_scan_a<<<NS / 256, 256, 0, stream>>>(cntT, offsT, bsum);
  k_scan_b<<<1, 1024, 0, stream>>>(bsum, bsum2);
  k_scatter<<<NBLK, 256, 0, stream>>>(esrc, edst, etyp, enorm, offsT, bsum2, rec);
  k_nsort<<<NBUK, 256, 0, stream>>>(bsum2, rec, noffs);
  k_ngather<<<(NN * 64 + 255) / 256, 256, 0, stream>>>(rec, noffs, bsum2, X, bias, out);
}

// Round 14
// 103.187 us; speedup vs baseline: 1.1336x; 1.0607x over previous
//
#include <hip/hip_runtime.h>
#include <hip/hip_bf16.h>

// RGCN layer, MI355X (gfx950).
// R14 = R13 graph with the W-conversion unbundled again (R13 post-mortem: inlining
// fp32->bf16 transpose into every gemm block = 6.5M bank-conflict cycles, 58us; the
// one-time k_wt + clean 16B Wt staging measured 39.4us in R11).
//  K0 k_wt: W[r][k][o] fp32 -> Wt[r][o][k] bf16, one-time, 16 blocks.
//  K1 k_gemm_hist: blocks 0..255 = edge histogram (hides under gemm); blocks 256.. =
//     gemm (256 thr, 64 nodes x 4 rels, Wt staged to LDS via two short8 per thread).
//  K2 k_scan_a: per-bucket scan of 256 per-block counts (block == bucket).
//  K3 k_scan_b: scan 782 bucket totals -> bsum2[] global bucket starts.
//  K4 k_scatter: private counting-sort scatter; cursor = offsT_raw + bsum2[bucket].
//  K5 k_nsort: in-bucket sort by exact dst node -> per-node CSR noffs.
//  K6 k_ngather: wave-per-node rec-prefetch + shfl broadcast gather + bias + relu.
//
// ws: X 102.4MB | Wt 128KB | rec 8MB | cntT 800KB | offsT 800KB | bsum | bsum2 | noffs

#define NN 50000
#define EE 1000000
#define RR 16
#define NBLK 256            // binning blocks (hist/scatter)
#define EPB 3907            // ceil(EE/NBLK)
#define BSH 6               // 64 nodes per bucket
#define NBUK 782            // ceil(NN/64)
#define NS (NBUK * NBLK)    // 200192
#define SCAP 2048           // k_nsort LDS record capacity (mean 1279, +21 sigma)

typedef __attribute__((ext_vector_type(8))) short short8;
typedef __attribute__((ext_vector_type(4))) float f32x4;

static __device__ inline unsigned short f2bf(float f) {
  union { __hip_bfloat16 h; unsigned short u; } cv;
  cv.h = __float2bfloat16(f);
  return cv.u;
}
static __device__ inline float bf2f(unsigned short u) {
  union { unsigned i; float f; } cv;
  cv.i = ((unsigned)u) << 16;
  return cv.f;
}

// ---------------- K0: W[r][k][o] fp32 -> Wt[r][o][k] bf16 (one-time) ----------------
__global__ __launch_bounds__(256) void k_wt(const float* __restrict__ W,
                                            unsigned short* __restrict__ Wt) {
  __shared__ __align__(16) unsigned short Wl[64][72];
  const int r = blockIdx.x, tid = threadIdx.x;
  for (int i = tid; i < 4096; i += 256) Wl[i & 63][i >> 6] = f2bf(W[(r << 12) + i]);
  __syncthreads();
  const int o = tid >> 2, kc = (tid & 3) << 4;
  const short8 v0 = *reinterpret_cast<const short8*>(&Wl[o][kc]);
  const short8 v1 = *reinterpret_cast<const short8*>(&Wl[o][kc + 8]);
  unsigned short* dst = Wt + (r << 12) + (o << 6) + kc;
  *reinterpret_cast<short8*>(dst) = v0;
  *reinterpret_cast<short8*>(dst + 8) = v1;
}

// ---------------- K1: fused edge-histogram + dense transform ----------------
// Blocks [0, NBLK): histogram of edst into 782 buckets (per-block-private counts).
// Blocks [NBLK, NBLK + NBUK*4): gemm, bx = (g)>>2, r0 = ((g)&3)<<2.
// Gemm: A = Wt tile from LDS (row=o=c*16+lr, k=lg*8+j); B = nf in regs (col=node=lr);
// D: row = o_local = lg*4+reg (4 consecutive o in-lane), col = node = lr.
__global__ __launch_bounds__(256) void k_gemm_hist(const float* __restrict__ nf,
                                                   const unsigned short* __restrict__ Wt,
                                                   const int* __restrict__ edst,
                                                   unsigned short* __restrict__ X,
                                                   int* __restrict__ cntT) {
  __shared__ __align__(16) char smem[4 * 64 * 72 * 2];  // 36,864 B union
  const int bid = blockIdx.x, tid = threadIdx.x;
  if (bid < NBLK) {
    // ---- histogram path ----
    int* cnt = reinterpret_cast<int*>(smem);
    for (int i = tid; i < NBUK; i += 256) cnt[i] = 0;
    __syncthreads();
    const int e0 = bid * EPB, e1 = min(EE, e0 + EPB);
    for (int e = e0 + tid; e < e1; e += 256) atomicAdd(&cnt[edst[e] >> BSH], 1);
    __syncthreads();
    for (int i = tid; i < NBUK; i += 256) cntT[i * NBLK + bid] = cnt[i];
    return;
  }
  // ---- gemm path ----
  auto Wl = reinterpret_cast<unsigned short(*)[64][72]>(smem);
  const int g = bid - NBLK;
  const int bx = g >> 2, r0 = (g & 3) << 2;
  const int lane = tid & 63, wv = tid >> 6;
  const int lr = lane & 15, lg = lane >> 4;
  const int node = (bx << 6) + (wv << 4) + lr;
  // stage Wt[r0..r0+3] -> LDS: per relation, thread t copies 16 shorts (two short8)
  #pragma unroll
  for (int rr = 0; rr < 4; ++rr) {
    const unsigned short* src = Wt + (((size_t)(r0 + rr)) << 12) + (tid << 4);
    const short8 v0 = *reinterpret_cast<const short8*>(src);
    const short8 v1 = *reinterpret_cast<const short8*>(src + 8);
    unsigned short* dst = &Wl[rr][tid >> 2][(tid & 3) << 4];
    *reinterpret_cast<short8*>(dst) = v0;
    *reinterpret_cast<short8*>(dst + 8) = v1;
  }
  short8 bf0, bf1;
  if (node < NN) {
    const float* ap = nf + (size_t)node * 64 + lg * 8;
    float4 v0 = *reinterpret_cast<const float4*>(ap);
    float4 v1 = *reinterpret_cast<const float4*>(ap + 4);
    float4 v2 = *reinterpret_cast<const float4*>(ap + 32);
    float4 v3 = *reinterpret_cast<const float4*>(ap + 36);
    bf0 = short8{(short)f2bf(v0.x), (short)f2bf(v0.y), (short)f2bf(v0.z), (short)f2bf(v0.w),
                 (short)f2bf(v1.x), (short)f2bf(v1.y), (short)f2bf(v1.z), (short)f2bf(v1.w)};
    bf1 = short8{(short)f2bf(v2.x), (short)f2bf(v2.y), (short)f2bf(v2.z), (short)f2bf(v2.w),
                 (short)f2bf(v3.x), (short)f2bf(v3.y), (short)f2bf(v3.z), (short)f2bf(v3.w)};
  } else {
    bf0 = short8{0, 0, 0, 0, 0, 0, 0, 0};
    bf1 = bf0;
  }
  __syncthreads();
  #pragma unroll
  for (int rr = 0; rr < 4; ++rr) {
    const int r = r0 + rr;
    short8 a[8];
    #pragma unroll
    for (int c = 0; c < 4; ++c) {
      a[2 * c] = *reinterpret_cast<const short8*>(&Wl[rr][(c << 4) + lr][lg << 3]);
      a[2 * c + 1] = *reinterpret_cast<const short8*>(&Wl[rr][(c << 4) + lr][32 + (lg << 3)]);
    }
    f32x4 acc[4];
    #pragma unroll
    for (int c = 0; c < 4; ++c) {
      acc[c] = f32x4{0.f, 0.f, 0.f, 0.f};
      acc[c] = __builtin_amdgcn_mfma_f32_16x16x32_bf16(a[2 * c], bf0, acc[c], 0, 0, 0);
      acc[c] = __builtin_amdgcn_mfma_f32_16x16x32_bf16(a[2 * c + 1], bf1, acc[c], 0, 0, 0);
    }
    if (node < NN) {
      #pragma unroll
      for (int c = 0; c < 4; ++c) {
        uint2 p;
        p.x = (unsigned)f2bf(acc[c][0]) | ((unsigned)f2bf(acc[c][1]) << 16);
        p.y = (unsigned)f2bf(acc[c][2]) | ((unsigned)f2bf(acc[c][3]) << 16);
        *reinterpret_cast<uint2*>(&X[((size_t)r * NN + node) * 64 + (c << 4) + (lg << 2)]) = p;
      }
    }
  }
}

// ---------------- K2: per-bucket scan of per-block counts ----------------
__global__ __launch_bounds__(256) void k_scan_a(const int* __restrict__ cntT,
                                                int* __restrict__ offsT,
                                                int* __restrict__ bsum) {
  __shared__ int s[256];
  const int t = threadIdx.x;
  const int i = blockIdx.x * 256 + t;
  const int v = cntT[i];
  s[t] = v;
  __syncthreads();
  #pragma unroll
  for (int off = 1; off < 256; off <<= 1) {
    const int x = (t >= off) ? s[t - off] : 0;
    __syncthreads();
    s[t] += x;
    __syncthreads();
  }
  offsT[i] = s[t] - v;  // exclusive within bucket (raw)
  if (t == 255) bsum[blockIdx.x] = s[255];  // bucket total
}

// ---------------- K3: scan bucket totals -> global bucket starts ----------------
__global__ __launch_bounds__(1024) void k_scan_b(const int* __restrict__ bsum,
                                                 int* __restrict__ bsum2) {
  __shared__ int s[1024];
  const int t = threadIdx.x;
  const int v = (t < NBUK) ? bsum[t] : 0;
  s[t] = v;
  __syncthreads();
  #pragma unroll
  for (int off = 1; off < 1024; off <<= 1) {
    const int x = (t >= off) ? s[t - off] : 0;
    __syncthreads();
    s[t] += x;
    __syncthreads();
  }
  if (t < NBUK) bsum2[t] = s[t] - v;  // global start of bucket t
  if (t == NBUK) bsum2[NBUK] = EE;
}

// ---------------- K4: private counting-sort scatter ----------------
__global__ __launch_bounds__(256) void k_scatter(const int* __restrict__ esrc,
                                                 const int* __restrict__ edst,
                                                 const int* __restrict__ etyp,
                                                 const float* __restrict__ enorm,
                                                 const int* __restrict__ offsT,
                                                 const int* __restrict__ bsum2,
                                                 uint2* __restrict__ rec) {
  __shared__ int cur[NBUK];
  const int bl = blockIdx.x, tid = threadIdx.x;
  for (int i = tid; i < NBUK; i += 256) cur[i] = offsT[i * NBLK + bl] + bsum2[i];
  __syncthreads();
  const int e0 = bl * EPB, e1 = min(EE, e0 + EPB);
  for (int e = e0 + tid; e < e1; e += 256) {
    const int d = edst[e];
    const int pos = atomicAdd(&cur[d >> BSH], 1);
    // pack: (typ*NN+src)<<6 | dstlow  (r.x>>6 == X row id, typ-major layout)
    rec[pos] = make_uint2(((unsigned)(etyp[e] * NN + esrc[e]) << 6) | (unsigned)(d & 63),
                          __float_as_uint(enorm[e]));
  }
}

// ---------------- K5: in-bucket sort by exact dst node (in place) ----------------
__global__ __launch_bounds__(256) void k_nsort(const int* __restrict__ bsum2,
                                               uint2* __restrict__ rec,
                                               int* __restrict__ noffs) {
  __shared__ uint2 sbuf[SCAP];  // 16 KB
  __shared__ int cnt[64], cur[64];
  const int bu = blockIdx.x, tid = threadIdx.x;
  const int s = bsum2[bu];
  const int e = bsum2[bu + 1];
  const int n = e - s;
  if (tid < 64) cnt[tid] = 0;
  __syncthreads();
  if (n > SCAP) {  // ~impossible overflow: leave unsorted, mark for slow gather
    if (tid < 64) noffs[(bu << BSH) + tid] = -1;
    return;
  }
  for (int i = tid; i < n; i += 256) {
    const uint2 r = rec[s + i];
    sbuf[i] = r;
    atomicAdd(&cnt[r.x & 63u], 1);  // native ds_add_u32
  }
  __syncthreads();
  if (tid < 64) {
    const int v = cnt[tid];
    int x = v;
    #pragma unroll
    for (int off = 1; off < 64; off <<= 1) {
      const int t = __shfl_up(x, off, 64);
      if (tid >= off) x += t;
    }
    cur[tid] = x - v;
    noffs[(bu << BSH) + tid] = s + x - v;
  }
  __syncthreads();
  for (int i = tid; i < n; i += 256) {
    const uint2 r = sbuf[i];
    const int pos = atomicAdd(&cur[r.x & 63u], 1);
    rec[s + pos] = r;
  }
}

// ---------------- K6: wave-per-node gather, rec-prefetch + shfl ----------------
__global__ __launch_bounds__(256) void k_ngather(const uint2* __restrict__ rec,
                                                 const int* __restrict__ noffs,
                                                 const int* __restrict__ bsum2,
                                                 const unsigned short* __restrict__ X,
                                                 const float* __restrict__ bias,
                                                 float* __restrict__ out) {
  const int w = (int)((blockIdx.x * 256 + threadIdx.x) >> 6);  // node id
  const int lane = threadIdx.x & 63;
  if (w >= NN) return;
  const int quarter = lane >> 4, d4 = lane & 15;
  const int bu = w >> BSH;
  float4 acc = {0.f, 0.f, 0.f, 0.f};
  const int jb = noffs[w];
  if (jb >= 0) {
    const int je = ((w & 63) == 63) ? bsum2[bu + 1] : noffs[w + 1];
    for (int base = jb; base < je; base += 64) {
      const int deg = min(64, je - base);
      unsigned rxs = 0;
      float rns = 0.f;
      if (lane < deg) {
        const uint2 r = rec[base + lane];
        rxs = r.x >> 6;  // X row id
        rns = __uint_as_float(r.y);
      }
      int u = 0;
      for (; u + 8 <= deg; u += 8) {  // 8 edges per body, 2 independent X loads
        const int i0 = u + quarter, i1 = u + 4 + quarter;
        const unsigned row0 = (unsigned)__shfl((int)rxs, i0, 64);
        const float n0 = __shfl(rns, i0, 64);
        const unsigned row1 = (unsigned)__shfl((int)rxs, i1, 64);
        const float n1 = __shfl(rns, i1, 64);
        const uint2 x0 = *reinterpret_cast<const uint2*>(X + (size_t)row0 * 64 + (d4 << 2));
        const uint2 x1 = *reinterpret_cast<const uint2*>(X + (size_t)row1 * 64 + (d4 << 2));
        acc.x = fmaf(n0, bf2f((unsigned short)(x0.x & 0xffffu)), acc.x);
        acc.y = fmaf(n0, bf2f((unsigned short)(x0.x >> 16)), acc.y);
        acc.z = fmaf(n0, bf2f((unsigned short)(x0.y & 0xffffu)), acc.z);
        acc.w = fmaf(n0, bf2f((unsigned short)(x0.y >> 16)), acc.w);
        acc.x = fmaf(n1, bf2f((unsigned short)(x1.x & 0xffffu)), acc.x);
        acc.y = fmaf(n1, bf2f((unsigned short)(x1.x >> 16)), acc.y);
        acc.z = fmaf(n1, bf2f((unsigned short)(x1.y & 0xffffu)), acc.z);
        acc.w = fmaf(n1, bf2f((unsigned short)(x1.y >> 16)), acc.w);
      }
      for (; u < deg; u += 4) {  // remainder: clamp + zero-norm for invalid quarters
        const int i = u + quarter;
        const int ic = min(i, deg - 1);
        const unsigned row = (unsigned)__shfl((int)rxs, ic, 64);
        float n = __shfl(rns, ic, 64);
        n = (i < deg) ? n : 0.f;
        const uint2 x = *reinterpret_cast<const uint2*>(X + (size_t)row * 64 + (d4 << 2));
        acc.x = fmaf(n, bf2f((unsigned short)(x.x & 0xffffu)), acc.x);
        acc.y = fmaf(n, bf2f((unsigned short)(x.x >> 16)), acc.y);
        acc.z = fmaf(n, bf2f((unsigned short)(x.y & 0xffffu)), acc.z);
        acc.w = fmaf(n, bf2f((unsigned short)(x.y >> 16)), acc.w);
      }
    }
  } else {
    // oversized-bucket fallback: quarter-0 lanes filter-scan the whole bucket
    if (quarter == 0) {
      const int s = bsum2[bu];
      const int e = bsum2[bu + 1];
      const unsigned dl = (unsigned)(w & 63);
      for (int j = s; j < e; ++j) {
        const uint2 r = rec[j];
        if ((r.x & 63u) == dl) {
          const float n = __uint_as_float(r.y);
          const uint2 x =
              *reinterpret_cast<const uint2*>(X + (size_t)(r.x >> 6) * 64 + (d4 << 2));
          acc.x = fmaf(n, bf2f((unsigned short)(x.x & 0xffffu)), acc.x);
          acc.y = fmaf(n, bf2f((unsigned short)(x.x >> 16)), acc.y);
          acc.z = fmaf(n, bf2f((unsigned short)(x.y & 0xffffu)), acc.z);
          acc.w = fmaf(n, bf2f((unsigned short)(x.y >> 16)), acc.w);
        }
      }
    }
  }
  // merge quarters: lanes {d4, d4+16, d4+32, d4+48} hold same dims
  acc.x += __shfl_xor(acc.x, 16, 64);
  acc.y += __shfl_xor(acc.y, 16, 64);
  acc.z += __shfl_xor(acc.z, 16, 64);
  acc.w += __shfl_xor(acc.w, 16, 64);
  acc.x += __shfl_xor(acc.x, 32, 64);
  acc.y += __shfl_xor(acc.y, 32, 64);
  acc.z += __shfl_xor(acc.z, 32, 64);
  acc.w += __shfl_xor(acc.w, 32, 64);
  if (quarter == 0) {
    const float4 b = reinterpret_cast<const float4*>(bias)[d4];
    float4 o;
    o.x = fmaxf(acc.x + b.x, 0.f);
    o.y = fmaxf(acc.y + b.y, 0.f);
    o.z = fmaxf(acc.z + b.z, 0.f);
    o.w = fmaxf(acc.w + b.w, 0.f);
    reinterpret_cast<float4*>(out)[(size_t)w * 16 + d4] = o;
  }
}

extern "C" void kernel_launch(void* const* d_in, const int* in_sizes, int n_in,
                              void* d_out, int out_size, void* d_ws, size_t ws_size,
                              hipStream_t stream) {
  const float* nf = (const float*)d_in[0];
  const int* esrc = (const int*)d_in[1];
  const int* edst = (const int*)d_in[2];
  const int* etyp = (const int*)d_in[3];
  const float* enorm = (const float*)d_in[4];
  const float* W = (const float*)d_in[5];
  const float* bias = (const float*)d_in[6];
  float* out = (float*)d_out;

  char* ws = (char*)d_ws;
  unsigned short* X = (unsigned short*)ws;                 // 102,400,000 B
  unsigned short* Wt = (unsigned short*)(ws + 102400000);  //     131,072 B
  uint2* rec = (uint2*)(ws + 102531072);                   //   8,000,000 B
  int* cntT = (int*)(ws + 110531072);                      //     800,768 B
  int* offsT = (int*)(ws + 111331840);                     //     800,768 B
  int* bsum = (int*)(ws + 112132608);                      //       3,128 B
  int* bsum2 = (int*)(ws + 112135736);                     //       3,132 B
  int* noffs = (int*)(ws + 112138868);                     //     200,192 B

  k_wt<<<RR, 256, 0, stream>>>(W, Wt);
  k_gemm_hist<<<NBLK + NBUK * 4, 256, 0, stream>>>(nf, Wt, edst, X, cntT);
  k_scan_a<<<NS / 256, 256, 0, stream>>>(cntT, offsT, bsum);
  k_scan_b<<<1, 1024, 0, stream>>>(bsum, bsum2);
  k_scatter<<<NBLK, 256, 0, stream>>>(esrc, edst, etyp, enorm, offsT, bsum2, rec);
  k_nsort<<<NBUK, 256, 0, stream>>>(bsum2, rec, noffs);
  k_ngather<<<(NN * 64 + 255) / 256, 256, 0, stream>>>(rec, noffs, bsum2, X, bias, out);
}